// Round 1
// baseline (9029.077 us; speedup 1.0000x reference)
//
#include <hip/hip_runtime.h>
#include <cmath>

#define A_TOT 76725
#define A_PAD 76728   // padded to multiple of 4 for vector loads
#define NBATCH 8
#define NCLS 80
#define NANCH 9
#define NOUT 200

// ---------------------------------------------------------------------------
// prep: per (batch, spatial loc, anchor): class max/argmax, sigmoid (double),
// conf threshold, box decode (double). Layout note: logits level i is
// [B, 9*80, s]; channel for (a,c) = a*80+c; anchor row = base + loc*9 + a.
// ---------------------------------------------------------------------------
__global__ void prep_kernel(const float* __restrict__ logits,
                            const float* __restrict__ regress,
                            const float* __restrict__ anchors,
                            double* __restrict__ scores,
                            int* __restrict__ cats,
                            double* __restrict__ boxes,
                            int s, int base)
{
    const int loc = blockIdx.x * blockDim.x + threadIdx.x;
    const int b = blockIdx.y;
    if (loc >= s) return;

    const float* lg = logits + ((size_t)b * NANCH * NCLS) * s + loc;
    const float* rg = regress + ((size_t)b * NANCH * 4) * s + loc;

    for (int a = 0; a < NANCH; ++a) {
        // argmax over classes on raw logits (== argmax of sigmoid; first-index ties)
        const float* lga = lg + (size_t)a * NCLS * s;
        float mv = lga[0];
        int mc = 0;
        #pragma unroll 8
        for (int c = 1; c < NCLS; ++c) {
            float v = lga[(size_t)c * s];
            if (v > mv) { mv = v; mc = c; }
        }
        double sg = 1.0 / (1.0 + exp(-(double)mv));
        double key = (sg >= 0.6) ? sg : -1.0;

        const float* rga = rg + (size_t)a * 4 * s;
        double d0 = (double)rga[0];
        double d1 = (double)rga[(size_t)s];
        double d2 = (double)rga[(size_t)2 * s];
        double d3 = (double)rga[(size_t)3 * s];

        const int arow = base + loc * NANCH + a;
        double ax1 = (double)anchors[arow * 4 + 0];
        double ay1 = (double)anchors[arow * 4 + 1];
        double ax2 = (double)anchors[arow * 4 + 2];
        double ay2 = (double)anchors[arow * 4 + 3];
        double aw = ax2 - ax1, ah = ay2 - ay1;
        double acx = ax1 + 0.5 * aw, acy = ay1 + 0.5 * ah;
        double cx = acx + d0 * aw, cy = acy + d1 * ah;
        double w = aw * exp(d2), h = ah * exp(d3);

        size_t o = (size_t)b * A_PAD + arow;
        scores[o] = key;
        cats[o] = mc;
        double* bx = boxes + o * 4;
        bx[0] = cx - 0.5 * w;
        bx[1] = cy - 0.5 * h;
        bx[2] = cx + 0.5 * w;
        bx[3] = cy + 0.5 * h;
    }
}

// ---------------------------------------------------------------------------
// NMS: one block per batch. 200 iterations; each fuses suppression from the
// previous pick with the next block-wide argmax (single pass over scores).
// Class-distance <=4 prefilter is safe: class offset = 1280/class; all boxes
// lie within a span < 4600 pre-shift, so |dcat|>=4 can never overlap.
// ---------------------------------------------------------------------------
__launch_bounds__(1024, 1)
__global__ void nms_kernel(double* __restrict__ scores,
                           const int* __restrict__ cats,
                           const double* __restrict__ boxes,
                           float* __restrict__ out)
{
    const int b = blockIdx.x;
    const int tid = threadIdx.x;
    double* S = scores + (size_t)b * A_PAD;
    const int* C = cats + (size_t)b * A_PAD;
    const double* BX = boxes + (size_t)b * A_PAD * 4;
    float* O = out + (size_t)b * NOUT * 6;

    __shared__ double sval[1024];
    __shared__ int sidx[1024];
    __shared__ double pick[5];   // shifted x1,y1,x2,y2, area
    __shared__ int pickcat;
    __shared__ int pickvalid;

    // init pad entries every call (ws is re-poisoned)
    if (tid < A_PAD - A_TOT) S[A_TOT + tid] = -1.0;
    __syncthreads();

    bool sup = false;
    for (int t = 0; t < NOUT; ++t) {
        double px1 = 0, py1 = 0, px2 = 0, py2 = 0, pa = 0;
        int pc = 0;
        if (sup) {
            px1 = pick[0]; py1 = pick[1]; px2 = pick[2]; py2 = pick[3];
            pa = pick[4]; pc = pickcat;
        }

        double best = -1e300;
        int bestj = 0;
        for (int j0 = tid * 4; j0 < A_PAD; j0 += 4096) {
            double2 s01 = *(const double2*)(S + j0);
            double2 s23 = *(const double2*)(S + j0 + 2);
            int4 c4 = *(const int4*)(C + j0);
            double ss[4] = {s01.x, s01.y, s23.x, s23.y};
            int cc[4] = {c4.x, c4.y, c4.z, c4.w};
            #pragma unroll
            for (int k = 0; k < 4; ++k) {
                int j = j0 + k;
                double sv = ss[k];
                if (sup && sv >= 0.0) {
                    int cd = cc[k] - pc;
                    if (cd < 0) cd = -cd;
                    if (cd <= 4) {
                        const double* bb = BX + (size_t)j * 4;
                        double shift = (double)cc[k] * 1280.0;
                        double x1 = bb[0] + shift, y1 = bb[1] + shift;
                        double x2 = bb[2] + shift, y2 = bb[3] + shift;
                        double ix1 = px1 > x1 ? px1 : x1;
                        double iy1 = py1 > y1 ? py1 : y1;
                        double ix2 = px2 < x2 ? px2 : x2;
                        double iy2 = py2 < y2 ? py2 : y2;
                        double iw = ix2 - ix1; if (iw < 0.0) iw = 0.0;
                        double ih = iy2 - iy1; if (ih < 0.0) ih = 0.0;
                        double inter = iw * ih;
                        double areaj = (x2 - x1) * (y2 - y1);
                        double iou = inter / (pa + areaj - inter + 1e-9);
                        if (iou > 0.5) { sv = -1.0; S[j] = -1.0; }
                    }
                }
                // ascending j within thread: '>' keeps first occurrence
                if (sv > best) { best = sv; bestj = j; }
            }
        }

        sval[tid] = best;
        sidx[tid] = bestj;
        __syncthreads();
        for (int off = 512; off > 0; off >>= 1) {
            if (tid < off) {
                double v2 = sval[tid + off];
                int j2 = sidx[tid + off];
                if (v2 > sval[tid] || (v2 == sval[tid] && j2 < sidx[tid])) {
                    sval[tid] = v2; sidx[tid] = j2;
                }
            }
            __syncthreads();
        }

        if (tid == 0) {
            int j = sidx[0];
            double sc = sval[0];
            int valid = (sc > 0.0) ? 1 : 0;
            if (valid) {
                const double* bb = BX + (size_t)j * 4;
                int c = C[j];
                O[t * 6 + 0] = (float)bb[0];
                O[t * 6 + 1] = (float)bb[1];
                O[t * 6 + 2] = (float)bb[2];
                O[t * 6 + 3] = (float)bb[3];
                O[t * 6 + 4] = (float)sc;
                O[t * 6 + 5] = (float)c;
                double shift = (double)c * 1280.0;
                double x1 = bb[0] + shift, y1 = bb[1] + shift;
                double x2 = bb[2] + shift, y2 = bb[3] + shift;
                pick[0] = x1; pick[1] = y1; pick[2] = x2; pick[3] = y2;
                pick[4] = (x2 - x1) * (y2 - y1);
                pickcat = c;
                S[j] = -1.0;   // chosen box removed before next argmax
            } else {
                O[t * 6 + 0] = 0.0f; O[t * 6 + 1] = 0.0f;
                O[t * 6 + 2] = 0.0f; O[t * 6 + 3] = 0.0f;
                O[t * 6 + 4] = 0.0f; O[t * 6 + 5] = -1.0f;
            }
            pickvalid = valid;
        }
        __syncthreads();
        sup = (pickvalid != 0);
    }
}

extern "C" void kernel_launch(void* const* d_in, const int* in_sizes, int n_in,
                              void* d_out, int out_size, void* d_ws, size_t ws_size,
                              hipStream_t stream)
{
    // dict order: logits_0, regress_0, logits_1, regress_1, ..., anchors
    const float* anchors = (const float*)d_in[10];

    double* scores = (double*)d_ws;                                      // 8*A_PAD*8  B
    int* cats = (int*)((char*)d_ws + (size_t)NBATCH * A_PAD * 8);        // 8*A_PAD*4  B
    double* boxes = (double*)((char*)d_ws + (size_t)NBATCH * A_PAD * 12); // 8*A_PAD*32 B

    static const int spatial[5] = {6400, 1600, 400, 100, 25};
    static const int base[5] = {0, 57600, 72000, 75600, 76500};

    for (int l = 0; l < 5; ++l) {
        dim3 g((spatial[l] + 255) / 256, NBATCH);
        prep_kernel<<<g, 256, 0, stream>>>(
            (const float*)d_in[2 * l], (const float*)d_in[2 * l + 1],
            anchors, scores, cats, boxes, spatial[l], base[l]);
    }
    nms_kernel<<<NBATCH, 1024, 0, stream>>>(scores, cats, boxes, (float*)d_out);
}

// Round 2
// 4053.428 us; speedup vs baseline: 2.2275x; 2.2275x over previous
//
#include <hip/hip_runtime.h>
#include <cmath>

#define A_TOT 76725
#define A_PAD 76728   // multiple of 4
#define NBATCH 8
#define NCLS 80
#define NANCH 9
#define NOUT 200

#define NBPB 16                 // NMS blocks per batch
#define NBLK (NBATCH * NBPB)    // 128 total blocks (<= 256 CUs -> co-resident)
#define SLICE 4800              // anchors per block slice (16*4800 >= A_PAD)
#define NMS_THREADS 256

// ---------------------------------------------------------------------------
// shared f64 emit: sigmoid + threshold + box decode, identical expressions to
// the round-1 kernel (absmax 0.0 vs np ref) — do not reorder these ops.
// ---------------------------------------------------------------------------
__device__ __forceinline__ void emit_anchor(const float* __restrict__ anchors,
                                            double* __restrict__ scores,
                                            int* __restrict__ cats,
                                            double* __restrict__ boxes,
                                            int b, int arow, float mv, int mc,
                                            float f0, float f1, float f2, float f3)
{
    double sg = 1.0 / (1.0 + exp(-(double)mv));
    double key = (sg >= 0.6) ? sg : -1.0;

    double d0 = (double)f0, d1 = (double)f1, d2 = (double)f2, d3 = (double)f3;

    const float4 av = *(const float4*)(anchors + (size_t)arow * 4);
    double ax1 = (double)av.x, ay1 = (double)av.y;
    double ax2 = (double)av.z, ay2 = (double)av.w;
    double aw = ax2 - ax1, ah = ay2 - ay1;
    double acx = ax1 + 0.5 * aw, acy = ay1 + 0.5 * ah;
    double cx = acx + d0 * aw, cy = acy + d1 * ah;
    double w = aw * exp(d2), h = ah * exp(d3);

    size_t o = (size_t)b * A_PAD + arow;
    scores[o] = key;
    cats[o] = mc;
    double* bxp = boxes + o * 4;
    bxp[0] = cx - 0.5 * w;
    bxp[1] = cy - 0.5 * h;
    bxp[2] = cx + 0.5 * w;
    bxp[3] = cy + 0.5 * h;
}

// ---------------------------------------------------------------------------
// fused prep: grid (12 chunks, 9 anchors, 8 batch), 256 thr; thread = 4 locs.
// float4 vectorized class-max (levels with s%4==0), scalar fallback for s=25.
// ---------------------------------------------------------------------------
__global__ void prep_kernel(const float* __restrict__ lg0, const float* __restrict__ rg0,
                            const float* __restrict__ lg1, const float* __restrict__ rg1,
                            const float* __restrict__ lg2, const float* __restrict__ rg2,
                            const float* __restrict__ lg3, const float* __restrict__ rg3,
                            const float* __restrict__ lg4, const float* __restrict__ rg4,
                            const float* __restrict__ anchors,
                            double* __restrict__ scores,
                            int* __restrict__ cats,
                            double* __restrict__ boxes)
{
    const int bx = blockIdx.x;
    const int a  = blockIdx.y;
    const int b  = blockIdx.z;
    int lvl, chunk;
    if (bx < 7)      { lvl = 0; chunk = bx; }
    else if (bx < 9) { lvl = 1; chunk = bx - 7; }
    else             { lvl = bx - 7; chunk = 0; }

    const int   sarr[5] = {6400, 1600, 400, 100, 25};
    const int   barr[5] = {0, 57600, 72000, 75600, 76500};
    const float* lgs[5] = {lg0, lg1, lg2, lg3, lg4};
    const float* rgs[5] = {rg0, rg1, rg2, rg3, rg4};
    const int s = sarr[lvl], base = barr[lvl];
    const float* lg = lgs[lvl];
    const float* rg = rgs[lvl];

    const int loc0 = chunk * 1024 + threadIdx.x * 4;
    if (loc0 >= s) return;

    const float* lga = lg + ((size_t)(b * NANCH + a) * NCLS) * s + loc0;
    const float* rga = rg + ((size_t)(b * NANCH + a) * 4) * s + loc0;

    if ((s & 3) == 0) {
        // fast path: 16B-aligned float4 columns
        float4 m = *(const float4*)lga;
        int mcx = 0, mcy = 0, mcz = 0, mcw = 0;
        #pragma unroll 8
        for (int c = 1; c < NCLS; ++c) {
            float4 v = *(const float4*)(lga + (size_t)c * s);
            if (v.x > m.x) { m.x = v.x; mcx = c; }
            if (v.y > m.y) { m.y = v.y; mcy = c; }
            if (v.z > m.z) { m.z = v.z; mcz = c; }
            if (v.w > m.w) { m.w = v.w; mcw = c; }
        }
        float4 r0 = *(const float4*)(rga);
        float4 r1 = *(const float4*)(rga + (size_t)s);
        float4 r2 = *(const float4*)(rga + 2 * (size_t)s);
        float4 r3 = *(const float4*)(rga + 3 * (size_t)s);

        const float* mp  = (const float*)&m;
        const int    mci[4] = {mcx, mcy, mcz, mcw};
        const float* p0 = (const float*)&r0;
        const float* p1 = (const float*)&r1;
        const float* p2 = (const float*)&r2;
        const float* p3 = (const float*)&r3;
        #pragma unroll
        for (int j = 0; j < 4; ++j) {
            const int arow = base + (loc0 + j) * NANCH + a;
            emit_anchor(anchors, scores, cats, boxes, b, arow,
                        mp[j], mci[j], p0[j], p1[j], p2[j], p3[j]);
        }
    } else {
        // scalar path (s == 25)
        for (int j = 0; j < 4; ++j) {
            const int loc = loc0 + j;
            if (loc >= s) break;
            const float* l1 = lga + j;
            float mv = l1[0];
            int mc = 0;
            #pragma unroll 8
            for (int c = 1; c < NCLS; ++c) {
                float v = l1[(size_t)c * s];
                if (v > mv) { mv = v; mc = c; }
            }
            const float* r1 = rga + j;
            const int arow = base + loc * NANCH + a;
            emit_anchor(anchors, scores, cats, boxes, b, arow, mv, mc,
                        r1[0], r1[(size_t)s], r1[2 * (size_t)s], r1[3 * (size_t)s]);
        }
    }
}

// ---------------------------------------------------------------------------
// device-scope grid barrier: monotonic counter, one arrive per block.
// Safe: NBLK=128 blocks <= 256 CUs, nothing else resident -> all co-resident.
// ---------------------------------------------------------------------------
__device__ __forceinline__ void grid_barrier(unsigned* counter, unsigned target)
{
    __syncthreads();
    if (threadIdx.x == 0) {
        __hip_atomic_fetch_add(counter, 1u, __ATOMIC_ACQ_REL, __HIP_MEMORY_SCOPE_AGENT);
        while (__hip_atomic_load(counter, __ATOMIC_ACQUIRE, __HIP_MEMORY_SCOPE_AGENT) < target) {
            __builtin_amdgcn_s_sleep(2);
        }
    }
    __syncthreads();
}

__global__ void init_kernel(unsigned* counter) { *counter = 0u; }

// ---------------------------------------------------------------------------
// NMS: 128 persistent blocks (16/batch), score+cat slices in LDS.
// Per pick: local LDS argmax -> parity-double-buffered candidate -> one grid
// barrier -> redundant 16-way winner reduce -> local LDS suppression.
// f64 IoU with shifted coords copied verbatim from round 1 (bit-exact).
// ---------------------------------------------------------------------------
__launch_bounds__(NMS_THREADS, 1)
__global__ void nms_kernel(const double* __restrict__ scores,
                           const int* __restrict__ cats,
                           const double* __restrict__ boxes,
                           double* __restrict__ cand_v,   // [2][NBLK]
                           int* __restrict__ cand_i,      // [2][NBLK]
                           unsigned* __restrict__ counter,
                           float* __restrict__ out)
{
    const int blk = blockIdx.x;
    const int b   = blk / NBPB;
    const int bl  = blk % NBPB;
    const int tid = threadIdx.x;
    const int lo  = bl * SLICE;
    const int cnt = min(SLICE, A_PAD - lo);

    const double* BX = boxes + (size_t)b * A_PAD * 4;
    const int*    CT = cats + (size_t)b * A_PAD;

    __shared__ double S[SLICE];
    __shared__ int    C[SLICE];
    __shared__ double rv[NMS_THREADS];
    __shared__ int    ri[NMS_THREADS];
    __shared__ double wbox[5];     // shifted x1,y1,x2,y2, area
    __shared__ double wval_s;
    __shared__ int    wcat_s, wvalid_s, widx_s;

    for (int i = tid; i < SLICE; i += NMS_THREADS) {
        const int g = lo + i;
        if (i < cnt && g < A_TOT) {
            S[i] = scores[(size_t)b * A_PAD + g];
            C[i] = CT[g];
        } else {
            S[i] = -1.0;
            C[i] = 0;
        }
    }
    __syncthreads();

    for (int t = 0; t < NOUT; ++t) {
        // ---- local argmax over slice (ascending idx; '>' keeps first) ----
        double best = -1.0e300;
        int bi = 0x7fffffff;
        for (int i = tid; i < SLICE; i += NMS_THREADS) {
            double v = S[i];
            if (v > best) { best = v; bi = lo + i; }
        }
        rv[tid] = best;
        ri[tid] = bi;
        __syncthreads();
        for (int off = NMS_THREADS / 2; off > 0; off >>= 1) {
            if (tid < off) {
                double v2 = rv[tid + off];
                int    i2 = ri[tid + off];
                if (v2 > rv[tid] || (v2 == rv[tid] && i2 < ri[tid])) {
                    rv[tid] = v2; ri[tid] = i2;
                }
            }
            __syncthreads();
        }
        const int par = t & 1;
        if (tid == 0) {
            cand_v[par * NBLK + blk] = rv[0];
            cand_i[par * NBLK + blk] = ri[0];
        }

        grid_barrier(counter, (unsigned)((t + 1) * NBLK));

        // ---- redundant winner reduce + broadcast ----
        if (tid == 0) {
            double wv = -1.0e300;
            int wi = 0x7fffffff;
            for (int k = 0; k < NBPB; ++k) {
                double v  = cand_v[par * NBLK + b * NBPB + k];
                int    i2 = cand_i[par * NBLK + b * NBPB + k];
                if (v > wv || (v == wv && i2 < wi)) { wv = v; wi = i2; }
            }
            const int valid = (wv > 0.0) ? 1 : 0;
            wvalid_s = valid;
            widx_s = wi;
            wval_s = wv;
            if (valid) {
                const int c = CT[wi];
                const double* bb = BX + (size_t)wi * 4;
                double b0 = bb[0], b1 = bb[1], b2 = bb[2], b3 = bb[3];
                double shift = (double)c * 1280.0;
                double x1 = b0 + shift, y1 = b1 + shift;
                double x2 = b2 + shift, y2 = b3 + shift;
                wbox[0] = x1; wbox[1] = y1; wbox[2] = x2; wbox[3] = y2;
                wbox[4] = (x2 - x1) * (y2 - y1);
                wcat_s = c;
                if (wi >= lo && wi < lo + SLICE) S[wi - lo] = -1.0;  // remove pick
                if (bl == 0) {
                    float* O = out + ((size_t)b * NOUT + t) * 6;
                    O[0] = (float)b0; O[1] = (float)b1;
                    O[2] = (float)b2; O[3] = (float)b3;
                    O[4] = (float)wv; O[5] = (float)c;
                }
            } else if (bl == 0) {
                float* O = out + ((size_t)b * NOUT + t) * 6;
                O[0] = 0.0f; O[1] = 0.0f; O[2] = 0.0f; O[3] = 0.0f;
                O[4] = 0.0f; O[5] = -1.0f;
            }
        }
        __syncthreads();

        // ---- local suppression ----
        if (wvalid_s) {
            const double px1 = wbox[0], py1 = wbox[1];
            const double px2 = wbox[2], py2 = wbox[3];
            const double pa = wbox[4];
            const int pc = wcat_s;
            for (int i = tid; i < cnt; i += NMS_THREADS) {
                double sv = S[i];
                if (sv >= 0.0) {
                    int cd = C[i] - pc;
                    if (cd < 0) cd = -cd;
                    if (cd <= 4) {
                        const double* bb = BX + (size_t)(lo + i) * 4;
                        double shift = (double)C[i] * 1280.0;
                        double x1 = bb[0] + shift, y1 = bb[1] + shift;
                        double x2 = bb[2] + shift, y2 = bb[3] + shift;
                        double ix1 = px1 > x1 ? px1 : x1;
                        double iy1 = py1 > y1 ? py1 : y1;
                        double ix2 = px2 < x2 ? px2 : x2;
                        double iy2 = py2 < y2 ? py2 : y2;
                        double iw = ix2 - ix1; if (iw < 0.0) iw = 0.0;
                        double ih = iy2 - iy1; if (ih < 0.0) ih = 0.0;
                        double inter = iw * ih;
                        double areaj = (x2 - x1) * (y2 - y1);
                        double iou = inter / (pa + areaj - inter + 1e-9);
                        if (iou > 0.5) S[i] = -1.0;
                    }
                }
            }
        }
        __syncthreads();
    }
}

extern "C" void kernel_launch(void* const* d_in, const int* in_sizes, int n_in,
                              void* d_out, int out_size, void* d_ws, size_t ws_size,
                              hipStream_t stream)
{
    // dict order: logits_0, regress_0, logits_1, regress_1, ..., anchors
    const float* anchors = (const float*)d_in[10];

    char* ws = (char*)d_ws;
    double* scores = (double*)ws;                                   // 8*A_PAD*8
    int*    cats   = (int*)(ws + (size_t)NBATCH * A_PAD * 8);       // 8*A_PAD*4
    double* boxes  = (double*)(ws + (size_t)NBATCH * A_PAD * 12);   // 8*A_PAD*32
    size_t off = (size_t)NBATCH * A_PAD * 44;
    double* cand_v = (double*)(ws + off); off += 2 * NBLK * sizeof(double);
    int*    cand_i = (int*)(ws + off);    off += 2 * NBLK * sizeof(int);
    unsigned* counter = (unsigned*)(ws + off);

    init_kernel<<<1, 1, 0, stream>>>(counter);

    prep_kernel<<<dim3(12, NANCH, NBATCH), 256, 0, stream>>>(
        (const float*)d_in[0], (const float*)d_in[1],
        (const float*)d_in[2], (const float*)d_in[3],
        (const float*)d_in[4], (const float*)d_in[5],
        (const float*)d_in[6], (const float*)d_in[7],
        (const float*)d_in[8], (const float*)d_in[9],
        anchors, scores, cats, boxes);

    nms_kernel<<<NBLK, NMS_THREADS, 0, stream>>>(
        scores, cats, boxes, cand_v, cand_i, counter, (float*)d_out);
}

// Round 3
// 564.936 us; speedup vs baseline: 15.9825x; 7.1750x over previous
//
#include <hip/hip_runtime.h>
#include <cmath>

#define A_TOT 76725
#define A_PAD 76728   // multiple of 4
#define NBATCH 8
#define NCLS 80
#define NANCH 9
#define NOUT 200

#define MCAP 2048     // compacted-candidate capacity (power of two, bitonic)
#define NCACHE 512    // sorted candidates whose boxes are cached in LDS
#define NTH 1024
#define NBUCK 4096
#define UKEY_BASE 0x3FE33333u   // upper32 bits of f64(0.6)

// ---------------------------------------------------------------------------
// shared f64 emit: sigmoid + threshold + box decode, identical expressions to
// the round-1/2 kernels (absmax 0.0 vs np ref) — do not reorder these ops.
// ---------------------------------------------------------------------------
__device__ __forceinline__ void emit_anchor(const float* __restrict__ anchors,
                                            double* __restrict__ scores,
                                            int* __restrict__ cats,
                                            double* __restrict__ boxes,
                                            int b, int arow, float mv, int mc,
                                            float f0, float f1, float f2, float f3)
{
    double sg = 1.0 / (1.0 + exp(-(double)mv));
    double key = (sg >= 0.6) ? sg : -1.0;

    double d0 = (double)f0, d1 = (double)f1, d2 = (double)f2, d3 = (double)f3;

    const float4 av = *(const float4*)(anchors + (size_t)arow * 4);
    double ax1 = (double)av.x, ay1 = (double)av.y;
    double ax2 = (double)av.z, ay2 = (double)av.w;
    double aw = ax2 - ax1, ah = ay2 - ay1;
    double acx = ax1 + 0.5 * aw, acy = ay1 + 0.5 * ah;
    double cx = acx + d0 * aw, cy = acy + d1 * ah;
    double w = aw * exp(d2), h = ah * exp(d3);

    size_t o = (size_t)b * A_PAD + arow;
    scores[o] = key;
    cats[o] = mc;
    double* bxp = boxes + o * 4;
    bxp[0] = cx - 0.5 * w;
    bxp[1] = cy - 0.5 * h;
    bxp[2] = cx + 0.5 * w;
    bxp[3] = cy + 0.5 * h;
}

// ---------------------------------------------------------------------------
// fused prep: grid (12 chunks, 9 anchors, 8 batch), 256 thr; thread = 4 locs.
// ---------------------------------------------------------------------------
__global__ void prep_kernel(const float* __restrict__ lg0, const float* __restrict__ rg0,
                            const float* __restrict__ lg1, const float* __restrict__ rg1,
                            const float* __restrict__ lg2, const float* __restrict__ rg2,
                            const float* __restrict__ lg3, const float* __restrict__ rg3,
                            const float* __restrict__ lg4, const float* __restrict__ rg4,
                            const float* __restrict__ anchors,
                            double* __restrict__ scores,
                            int* __restrict__ cats,
                            double* __restrict__ boxes)
{
    const int bx = blockIdx.x;
    const int a  = blockIdx.y;
    const int b  = blockIdx.z;
    int lvl, chunk;
    if (bx < 7)      { lvl = 0; chunk = bx; }
    else if (bx < 9) { lvl = 1; chunk = bx - 7; }
    else             { lvl = bx - 7; chunk = 0; }

    const int   sarr[5] = {6400, 1600, 400, 100, 25};
    const int   barr[5] = {0, 57600, 72000, 75600, 76500};
    const float* lgs[5] = {lg0, lg1, lg2, lg3, lg4};
    const float* rgs[5] = {rg0, rg1, rg2, rg3, rg4};
    const int s = sarr[lvl], base = barr[lvl];
    const float* lg = lgs[lvl];
    const float* rg = rgs[lvl];

    const int loc0 = chunk * 1024 + threadIdx.x * 4;
    if (loc0 >= s) return;

    const float* lga = lg + ((size_t)(b * NANCH + a) * NCLS) * s + loc0;
    const float* rga = rg + ((size_t)(b * NANCH + a) * 4) * s + loc0;

    if ((s & 3) == 0) {
        float4 m = *(const float4*)lga;
        int mcx = 0, mcy = 0, mcz = 0, mcw = 0;
        #pragma unroll 8
        for (int c = 1; c < NCLS; ++c) {
            float4 v = *(const float4*)(lga + (size_t)c * s);
            if (v.x > m.x) { m.x = v.x; mcx = c; }
            if (v.y > m.y) { m.y = v.y; mcy = c; }
            if (v.z > m.z) { m.z = v.z; mcz = c; }
            if (v.w > m.w) { m.w = v.w; mcw = c; }
        }
        float4 r0 = *(const float4*)(rga);
        float4 r1 = *(const float4*)(rga + (size_t)s);
        float4 r2 = *(const float4*)(rga + 2 * (size_t)s);
        float4 r3 = *(const float4*)(rga + 3 * (size_t)s);

        const float* mp  = (const float*)&m;
        const int    mci[4] = {mcx, mcy, mcz, mcw};
        const float* p0 = (const float*)&r0;
        const float* p1 = (const float*)&r1;
        const float* p2 = (const float*)&r2;
        const float* p3 = (const float*)&r3;
        #pragma unroll
        for (int j = 0; j < 4; ++j) {
            const int arow = base + (loc0 + j) * NANCH + a;
            emit_anchor(anchors, scores, cats, boxes, b, arow,
                        mp[j], mci[j], p0[j], p1[j], p2[j], p3[j]);
        }
    } else {
        for (int j = 0; j < 4; ++j) {
            const int loc = loc0 + j;
            if (loc >= s) break;
            const float* l1 = lga + j;
            float mv = l1[0];
            int mc = 0;
            #pragma unroll 8
            for (int c = 1; c < NCLS; ++c) {
                float v = l1[(size_t)c * s];
                if (v > mv) { mv = v; mc = c; }
            }
            const float* r1 = rga + j;
            const int arow = base + loc * NANCH + a;
            emit_anchor(anchors, scores, cats, boxes, b, arow, mv, mc,
                        r1[0], r1[(size_t)s], r1[2 * (size_t)s], r1[3 * (size_t)s]);
        }
    }
}

// ---------------------------------------------------------------------------
// NMS: one block per batch. Sorted-scan greedy (provably identical to the
// reference's iterative argmax+suppress, incl. first-index tie-break).
// ---------------------------------------------------------------------------
__launch_bounds__(NTH, 1)
__global__ void nms_kernel(const double* __restrict__ scores,
                           const int* __restrict__ cats,
                           const double* __restrict__ boxes,
                           float* __restrict__ out)
{
    const int b = blockIdx.x;
    const int tid = threadIdx.x;
    const double* SC = scores + (size_t)b * A_PAD;
    const int*    CT = cats + (size_t)b * A_PAD;
    const double* BX = boxes + (size_t)b * A_PAD * 4;

    __shared__ unsigned long long skey[MCAP];   // 16 KB (reused as rv[] in fallback)
    __shared__ unsigned spay[MCAP];             // 8 KB  (reused as ri[] in fallback)
    __shared__ alignas(16) char ubuf[32768];    // hist -> boxcache/accepted/outbuf
    __shared__ int b_star_s, valid_s, cnt_s, acc_s;

    unsigned* ha = (unsigned*)ubuf;
    unsigned* hb = (unsigned*)(ubuf + 16384);

    // ---- phase 1: histogram of score-key upper bits --------------------
    for (int i = tid; i < NBUCK; i += NTH) ha[i] = 0u;
    if (tid == 0) cnt_s = 0;
    __syncthreads();
    for (int j = tid; j < A_TOT; j += NTH) {
        double s = SC[j];
        if (s > 0.0) {
            unsigned uk = (unsigned)((unsigned long long)__double_as_longlong(s) >> 32);
            int bk = (int)((uk - UKEY_BASE) >> 8);
            atomicAdd(&ha[bk], 1u);
        }
    }
    __syncthreads();

    // ---- suffix scan (Hillis-Steele, 12 passes) ------------------------
    unsigned* src = ha; unsigned* dst = hb;
    for (int off = 1; off < NBUCK; off <<= 1) {
        for (int i = tid; i < NBUCK; i += NTH)
            dst[i] = src[i] + ((i + off < NBUCK) ? src[i + off] : 0u);
        __syncthreads();
        unsigned* t = src; src = dst; dst = t;
    }
    // src[b] = #candidates with bucket >= b (non-increasing)
    for (int i = tid; i < NBUCK; i += NTH) {
        if (src[i] <= (unsigned)MCAP && (i == 0 || src[i - 1] > (unsigned)MCAP))
            b_star_s = i;
    }
    if (tid == 0) valid_s = (int)src[0];
    __syncthreads();
    const int bstar = b_star_s;
    const int valid = valid_s;

    // ---- phase 2: compact top candidates -------------------------------
    for (int j = tid; j < A_TOT; j += NTH) {
        double s = SC[j];
        if (s > 0.0) {
            long long bits = __double_as_longlong(s);
            unsigned uk = (unsigned)((unsigned long long)bits >> 32);
            int bk = (int)((uk - UKEY_BASE) >> 8);
            if (bk >= bstar) {
                int p = atomicAdd(&cnt_s, 1);
                skey[p] = (unsigned long long)bits;
                spay[p] = ((unsigned)j << 7) | (unsigned)CT[j];
            }
        }
    }
    __syncthreads();
    const int cnt = cnt_s;   // == src[bstar] <= MCAP
    for (int i = cnt + tid; i < MCAP; i += NTH) { skey[i] = 0ull; spay[i] = 0xFFFFFFFFu; }
    __syncthreads();

    // ---- phase 3: bitonic sort (key desc, payload asc) -----------------
    for (int k = 2; k <= MCAP; k <<= 1) {
        for (int j = k >> 1; j > 0; j >>= 1) {
            for (int i = tid; i < MCAP; i += NTH) {
                int ixj = i ^ j;
                if (ixj > i) {
                    unsigned long long ka = skey[i], kb = skey[ixj];
                    unsigned pa = spay[i], pb = spay[ixj];
                    bool before = (ka > kb) || (ka == kb && pa < pb);
                    bool dir = ((i & k) == 0);
                    if (before != dir) {
                        skey[i] = kb; skey[ixj] = ka;
                        spay[i] = pb; spay[ixj] = pa;
                    }
                }
            }
            __syncthreads();
        }
    }

    // ---- phase 4: re-purpose ubuf --------------------------------------
    double (*bc)[4] = (double(*)[4])ubuf;                 // 512*32   = 16384
    double* aX1 = (double*)(ubuf + 16384);                // 200*8*5  = 8000
    double* aY1 = aX1 + NOUT;
    double* aX2 = aY1 + NOUT;
    double* aY2 = aX2 + NOUT;
    double* aAR = aY2 + NOUT;
    int*   aCT  = (int*)(ubuf + 16384 + 8000);            // 800
    float* obuf = (float*)(ubuf + 16384 + 8800);          // 4800 -> ends 29984

    const int ncache = cnt < NCACHE ? cnt : NCACHE;
    for (int i = tid; i < ncache; i += NTH) {
        int idx = (int)(spay[i] >> 7);
        const double* bb = BX + (size_t)idx * 4;
        bc[i][0] = bb[0]; bc[i][1] = bb[1]; bc[i][2] = bb[2]; bc[i][3] = bb[3];
    }
    for (int i = tid; i < NOUT * 6; i += NTH)
        obuf[i] = ((i % 6) == 5) ? -1.0f : 0.0f;
    __syncthreads();

    // ---- phase 5: greedy sorted scan (wave 0) --------------------------
    if (tid < 64) {
        const int lane = tid;
        int acc = 0;
        for (int pos = 0; pos < cnt && acc < NOUT; ++pos) {
            unsigned pay = spay[pos];
            int idx = (int)(pay >> 7);
            int cat = (int)(pay & 127u);
            double b0, b1, b2, b3;
            if (pos < NCACHE) {
                b0 = bc[pos][0]; b1 = bc[pos][1]; b2 = bc[pos][2]; b3 = bc[pos][3];
            } else {
                const double* bb = BX + (size_t)idx * 4;
                b0 = bb[0]; b1 = bb[1]; b2 = bb[2]; b3 = bb[3];
            }
            double shift = (double)cat * 1280.0;
            double x1 = b0 + shift, y1 = b1 + shift;
            double x2 = b2 + shift, y2 = b3 + shift;
            double areaj = (x2 - x1) * (y2 - y1);
            bool sup = false;
            for (int r = lane; r < acc; r += 64) {
                int cd = aCT[r] - cat; if (cd < 0) cd = -cd;
                if (cd <= 4) {
                    double ix1 = aX1[r] > x1 ? aX1[r] : x1;
                    double iy1 = aY1[r] > y1 ? aY1[r] : y1;
                    double ix2 = aX2[r] < x2 ? aX2[r] : x2;
                    double iy2 = aY2[r] < y2 ? aY2[r] : y2;
                    double iw = ix2 - ix1; if (iw < 0.0) iw = 0.0;
                    double ih = iy2 - iy1; if (ih < 0.0) ih = 0.0;
                    double inter = iw * ih;
                    double iou = inter / (aAR[r] + areaj - inter + 1e-9);
                    if (iou > 0.5) sup = true;
                }
            }
            sup = (__any(sup ? 1 : 0) != 0);
            if (!sup) {
                if (lane == 0) {
                    aX1[acc] = x1; aY1[acc] = y1; aX2[acc] = x2; aY2[acc] = y2;
                    aAR[acc] = areaj; aCT[acc] = cat;
                    float* o = obuf + acc * 6;
                    o[0] = (float)b0; o[1] = (float)b1;
                    o[2] = (float)b2; o[3] = (float)b3;
                    o[4] = (float)__longlong_as_double((long long)skey[pos]);
                    o[5] = (float)cat;
                }
                acc++;
            }
        }
        if (lane == 0) acc_s = acc;
    }
    __syncthreads();
    int acc = acc_s;

    // ---- phase 6: exact fallback (pathological only) -------------------
    if (acc < NOUT && cnt < valid) {
        double* rv = (double*)skey;
        int*    ri = (int*)spay;
        while (acc < NOUT) {
            double best = -1.0;
            int bi = 0x7fffffff;
            for (int j = tid; j < A_TOT; j += NTH) {
                double s = SC[j];
                if (s > 0.0) {
                    int cat = CT[j];
                    const double* bb = BX + (size_t)j * 4;
                    double shift = (double)cat * 1280.0;
                    double x1 = bb[0] + shift, y1 = bb[1] + shift;
                    double x2 = bb[2] + shift, y2 = bb[3] + shift;
                    double areaj = (x2 - x1) * (y2 - y1);
                    bool dead = false;
                    for (int r = 0; r < acc && !dead; ++r) {
                        int cd = aCT[r] - cat; if (cd < 0) cd = -cd;
                        if (cd <= 4) {
                            double ix1 = aX1[r] > x1 ? aX1[r] : x1;
                            double iy1 = aY1[r] > y1 ? aY1[r] : y1;
                            double ix2 = aX2[r] < x2 ? aX2[r] : x2;
                            double iy2 = aY2[r] < y2 ? aY2[r] : y2;
                            double iw = ix2 - ix1; if (iw < 0.0) iw = 0.0;
                            double ih = iy2 - iy1; if (ih < 0.0) ih = 0.0;
                            double inter = iw * ih;
                            double iou = inter / (aAR[r] + areaj - inter + 1e-9);
                            if (iou > 0.5) dead = true;
                        }
                    }
                    if (!dead && s > best) { best = s; bi = j; }
                }
            }
            rv[tid] = best; ri[tid] = bi;
            __syncthreads();
            for (int off = NTH / 2; off > 0; off >>= 1) {
                if (tid < off) {
                    if (rv[tid + off] > rv[tid] ||
                        (rv[tid + off] == rv[tid] && ri[tid + off] < ri[tid])) {
                        rv[tid] = rv[tid + off]; ri[tid] = ri[tid + off];
                    }
                }
                __syncthreads();
            }
            if (rv[0] <= 0.0) break;
            if (tid == 0) {
                int j = ri[0];
                int cat = CT[j];
                const double* bb = BX + (size_t)j * 4;
                double shift = (double)cat * 1280.0;
                double x1 = bb[0] + shift, y1 = bb[1] + shift;
                double x2 = bb[2] + shift, y2 = bb[3] + shift;
                aX1[acc] = x1; aY1[acc] = y1; aX2[acc] = x2; aY2[acc] = y2;
                aAR[acc] = (x2 - x1) * (y2 - y1); aCT[acc] = cat;
                float* o = obuf + acc * 6;
                o[0] = (float)bb[0]; o[1] = (float)bb[1];
                o[2] = (float)bb[2]; o[3] = (float)bb[3];
                o[4] = (float)rv[0]; o[5] = (float)cat;
                acc_s = acc + 1;
            }
            __syncthreads();
            acc = acc_s;
        }
    }
    __syncthreads();

    // ---- phase 7: write output -----------------------------------------
    float* O = out + (size_t)b * NOUT * 6;
    for (int i = tid; i < NOUT * 6; i += NTH) O[i] = obuf[i];
}

extern "C" void kernel_launch(void* const* d_in, const int* in_sizes, int n_in,
                              void* d_out, int out_size, void* d_ws, size_t ws_size,
                              hipStream_t stream)
{
    const float* anchors = (const float*)d_in[10];

    char* ws = (char*)d_ws;
    double* scores = (double*)ws;                                   // 8*A_PAD*8
    int*    cats   = (int*)(ws + (size_t)NBATCH * A_PAD * 8);       // 8*A_PAD*4
    double* boxes  = (double*)(ws + (size_t)NBATCH * A_PAD * 12);   // 8*A_PAD*32

    prep_kernel<<<dim3(12, NANCH, NBATCH), 256, 0, stream>>>(
        (const float*)d_in[0], (const float*)d_in[1],
        (const float*)d_in[2], (const float*)d_in[3],
        (const float*)d_in[4], (const float*)d_in[5],
        (const float*)d_in[6], (const float*)d_in[7],
        (const float*)d_in[8], (const float*)d_in[9],
        anchors, scores, cats, boxes);

    nms_kernel<<<NBATCH, NTH, 0, stream>>>(scores, cats, boxes, (float*)d_out);
}

// Round 4
// 499.079 us; speedup vs baseline: 18.0915x; 1.1320x over previous
//
#include <hip/hip_runtime.h>
#include <cmath>

#define A_TOT 76725
#define A_PAD 76728   // multiple of 4
#define NBATCH 8
#define NCLS 80
#define NANCH 9
#define NOUT 200

#define MCAP 2048     // compacted-candidate capacity (power of two, bitonic)
#define NTH 1024
#define NBUCK 4096
#define CHUNK 64
#define UKEY_BASE 0x3FE33333u   // upper32 bits of f64(0.6)

// ---------------------------------------------------------------------------
// shared f64 emit: sigmoid + threshold + box decode, identical expressions to
// rounds 1-3 (absmax 0.0 vs np ref) — do not reorder these ops.
// ---------------------------------------------------------------------------
__device__ __forceinline__ void emit_anchor(const float* __restrict__ anchors,
                                            double* __restrict__ scores,
                                            int* __restrict__ cats,
                                            double* __restrict__ boxes,
                                            int b, int arow, float mv, int mc,
                                            float f0, float f1, float f2, float f3)
{
    double sg = 1.0 / (1.0 + exp(-(double)mv));
    double key = (sg >= 0.6) ? sg : -1.0;

    double d0 = (double)f0, d1 = (double)f1, d2 = (double)f2, d3 = (double)f3;

    const float4 av = *(const float4*)(anchors + (size_t)arow * 4);
    double ax1 = (double)av.x, ay1 = (double)av.y;
    double ax2 = (double)av.z, ay2 = (double)av.w;
    double aw = ax2 - ax1, ah = ay2 - ay1;
    double acx = ax1 + 0.5 * aw, acy = ay1 + 0.5 * ah;
    double cx = acx + d0 * aw, cy = acy + d1 * ah;
    double w = aw * exp(d2), h = ah * exp(d3);

    size_t o = (size_t)b * A_PAD + arow;
    scores[o] = key;
    cats[o] = mc;
    double* bxp = boxes + o * 4;
    bxp[0] = cx - 0.5 * w;
    bxp[1] = cy - 0.5 * h;
    bxp[2] = cx + 0.5 * w;
    bxp[3] = cy + 0.5 * h;
}

// ---------------------------------------------------------------------------
// fused prep: grid (12 chunks, 9 anchors, 8 batch), 256 thr; thread = 4 locs.
// (unchanged from round 3 for attribution)
// ---------------------------------------------------------------------------
__global__ void prep_kernel(const float* __restrict__ lg0, const float* __restrict__ rg0,
                            const float* __restrict__ lg1, const float* __restrict__ rg1,
                            const float* __restrict__ lg2, const float* __restrict__ rg2,
                            const float* __restrict__ lg3, const float* __restrict__ rg3,
                            const float* __restrict__ lg4, const float* __restrict__ rg4,
                            const float* __restrict__ anchors,
                            double* __restrict__ scores,
                            int* __restrict__ cats,
                            double* __restrict__ boxes)
{
    const int bx = blockIdx.x;
    const int a  = blockIdx.y;
    const int b  = blockIdx.z;
    int lvl, chunk;
    if (bx < 7)      { lvl = 0; chunk = bx; }
    else if (bx < 9) { lvl = 1; chunk = bx - 7; }
    else             { lvl = bx - 7; chunk = 0; }

    const int   sarr[5] = {6400, 1600, 400, 100, 25};
    const int   barr[5] = {0, 57600, 72000, 75600, 76500};
    const float* lgs[5] = {lg0, lg1, lg2, lg3, lg4};
    const float* rgs[5] = {rg0, rg1, rg2, rg3, rg4};
    const int s = sarr[lvl], base = barr[lvl];
    const float* lg = lgs[lvl];
    const float* rg = rgs[lvl];

    const int loc0 = chunk * 1024 + threadIdx.x * 4;
    if (loc0 >= s) return;

    const float* lga = lg + ((size_t)(b * NANCH + a) * NCLS) * s + loc0;
    const float* rga = rg + ((size_t)(b * NANCH + a) * 4) * s + loc0;

    if ((s & 3) == 0) {
        float4 m = *(const float4*)lga;
        int mcx = 0, mcy = 0, mcz = 0, mcw = 0;
        #pragma unroll 8
        for (int c = 1; c < NCLS; ++c) {
            float4 v = *(const float4*)(lga + (size_t)c * s);
            if (v.x > m.x) { m.x = v.x; mcx = c; }
            if (v.y > m.y) { m.y = v.y; mcy = c; }
            if (v.z > m.z) { m.z = v.z; mcz = c; }
            if (v.w > m.w) { m.w = v.w; mcw = c; }
        }
        float4 r0 = *(const float4*)(rga);
        float4 r1 = *(const float4*)(rga + (size_t)s);
        float4 r2 = *(const float4*)(rga + 2 * (size_t)s);
        float4 r3 = *(const float4*)(rga + 3 * (size_t)s);

        const float* mp  = (const float*)&m;
        const int    mci[4] = {mcx, mcy, mcz, mcw};
        const float* p0 = (const float*)&r0;
        const float* p1 = (const float*)&r1;
        const float* p2 = (const float*)&r2;
        const float* p3 = (const float*)&r3;
        #pragma unroll
        for (int j = 0; j < 4; ++j) {
            const int arow = base + (loc0 + j) * NANCH + a;
            emit_anchor(anchors, scores, cats, boxes, b, arow,
                        mp[j], mci[j], p0[j], p1[j], p2[j], p3[j]);
        }
    } else {
        for (int j = 0; j < 4; ++j) {
            const int loc = loc0 + j;
            if (loc >= s) break;
            const float* l1 = lga + j;
            float mv = l1[0];
            int mc = 0;
            #pragma unroll 8
            for (int c = 1; c < NCLS; ++c) {
                float v = l1[(size_t)c * s];
                if (v > mv) { mv = v; mc = c; }
            }
            const float* r1 = rga + j;
            const int arow = base + loc * NANCH + a;
            emit_anchor(anchors, scores, cats, boxes, b, arow, mv, mc,
                        r1[0], r1[(size_t)s], r1[2 * (size_t)s], r1[3 * (size_t)s]);
        }
    }
}

// ---------------------------------------------------------------------------
// NMS: one block per batch. Sorted-scan greedy == reference iterative
// argmax+suppress (incl. first-index tie-break). Phase 5 is chunk-parallel:
// 64 candidates tested vs accepted + intra-chunk 64x64 mask in parallel,
// then a 64-bit alive-mask serial walk (exact greedy order).
// ---------------------------------------------------------------------------
__launch_bounds__(NTH, 1)
__global__ void nms_kernel(const double* __restrict__ scores,
                           const int* __restrict__ cats,
                           const double* __restrict__ boxes,
                           float* __restrict__ out)
{
    const int b = blockIdx.x;
    const int tid = threadIdx.x;
    const double* SC = scores + (size_t)b * A_PAD;
    const int*    CT = cats + (size_t)b * A_PAD;
    const double* BX = boxes + (size_t)b * A_PAD * 4;

    __shared__ unsigned long long skey[MCAP];   // 16 KB (reused as rv[] in fallback)
    __shared__ unsigned spay[MCAP];             // 8 KB  (reused as ri[] in fallback)
    __shared__ alignas(16) char ubuf[32768];    // hist -> accepted/outbuf/chunk
    __shared__ int b_star_s, valid_s, cnt_s, acc_s;

    unsigned* ha = (unsigned*)ubuf;
    unsigned* hb = (unsigned*)(ubuf + 16384);

    // ---- phase 1: histogram of score-key upper bits --------------------
    for (int i = tid; i < NBUCK; i += NTH) ha[i] = 0u;
    if (tid == 0) { cnt_s = 0; b_star_s = NBUCK - 1; }
    __syncthreads();
    for (int j = tid; j < A_TOT; j += NTH) {
        double s = SC[j];
        if (s > 0.0) {
            unsigned uk = (unsigned)((unsigned long long)__double_as_longlong(s) >> 32);
            int bk = (int)((uk - UKEY_BASE) >> 8);
            atomicAdd(&ha[bk], 1u);
        }
    }
    __syncthreads();

    // ---- suffix scan (Hillis-Steele, 12 passes) ------------------------
    unsigned* src = ha; unsigned* dst = hb;
    for (int off = 1; off < NBUCK; off <<= 1) {
        for (int i = tid; i < NBUCK; i += NTH)
            dst[i] = src[i] + ((i + off < NBUCK) ? src[i + off] : 0u);
        __syncthreads();
        unsigned* t = src; src = dst; dst = t;
    }
    // src[i] = #candidates with bucket >= i (non-increasing)
    for (int i = tid; i < NBUCK; i += NTH) {
        if (src[i] <= (unsigned)MCAP && (i == 0 || src[i - 1] > (unsigned)MCAP))
            b_star_s = i;
    }
    if (tid == 0) valid_s = (int)src[0];
    __syncthreads();
    const int bstar = b_star_s;
    const int valid = valid_s;

    // ---- phase 2: compact top candidates -------------------------------
    for (int j = tid; j < A_TOT; j += NTH) {
        double s = SC[j];
        if (s > 0.0) {
            long long bits = __double_as_longlong(s);
            unsigned uk = (unsigned)((unsigned long long)bits >> 32);
            int bk = (int)((uk - UKEY_BASE) >> 8);
            if (bk >= bstar) {
                int p = atomicAdd(&cnt_s, 1);
                if (p < MCAP) {
                    skey[p] = (unsigned long long)bits;
                    spay[p] = ((unsigned)j << 7) | (unsigned)CT[j];
                }
            }
        }
    }
    __syncthreads();
    const int cnt = cnt_s < MCAP ? cnt_s : MCAP;
    for (int i = cnt + tid; i < MCAP; i += NTH) { skey[i] = 0ull; spay[i] = 0xFFFFFFFFu; }
    __syncthreads();

    // ---- phase 3: bitonic sort (key desc, payload asc) -----------------
    for (int k = 2; k <= MCAP; k <<= 1) {
        for (int j = k >> 1; j > 0; j >>= 1) {
            for (int i = tid; i < MCAP; i += NTH) {
                int ixj = i ^ j;
                if (ixj > i) {
                    unsigned long long ka = skey[i], kb = skey[ixj];
                    unsigned pa = spay[i], pb = spay[ixj];
                    bool before = (ka > kb) || (ka == kb && pa < pb);
                    bool dir = ((i & k) == 0);
                    if (before != dir) {
                        skey[i] = kb; skey[ixj] = ka;
                        spay[i] = pb; spay[ixj] = pa;
                    }
                }
            }
            __syncthreads();
        }
    }

    // ---- phase 4: re-purpose ubuf --------------------------------------
    double* aX1 = (double*)ubuf;                           // 200*8*5 = 8000
    double* aY1 = aX1 + NOUT;
    double* aX2 = aY1 + NOUT;
    double* aY2 = aX2 + NOUT;
    double* aAR = aY2 + NOUT;
    int*   aCT  = (int*)(ubuf + 8000);                     // 800
    float* obuf = (float*)(ubuf + 8800);                   // 4800
    double* cSX1 = (double*)(ubuf + 13600);                // 64*8 each
    double* cSY1 = (double*)(ubuf + 14112);
    double* cSX2 = (double*)(ubuf + 14624);
    double* cSY2 = (double*)(ubuf + 15136);
    double* cAR2 = (double*)(ubuf + 15648);
    double (*cUB)[4] = (double(*)[4])(ubuf + 16160);       // 64*32 = 2048
    int* cCat = (int*)(ubuf + 18208);                      // 256
    unsigned long long* cMask = (unsigned long long*)(ubuf + 18464);  // 512
    int* cSup = (int*)(ubuf + 18976);                      // 256

    for (int i = tid; i < NOUT * 6; i += NTH)
        obuf[i] = ((i % 6) == 5) ? -1.0f : 0.0f;
    __syncthreads();

    // ---- phase 5: chunk-parallel greedy sorted scan --------------------
    int acc = 0;
    for (int c0 = 0; c0 < cnt && acc < NOUT; c0 += CHUNK) {
        const int n = (cnt - c0) < CHUNK ? (cnt - c0) : CHUNK;

        // load chunk candidates into LDS (shifted coords, f64 verbatim)
        if (tid < n) {
            unsigned pay = spay[c0 + tid];
            int idx = (int)(pay >> 7);
            int cat = (int)(pay & 127u);
            const double* bb = BX + (size_t)idx * 4;
            double b0 = bb[0], b1 = bb[1], b2 = bb[2], b3 = bb[3];
            cUB[tid][0] = b0; cUB[tid][1] = b1; cUB[tid][2] = b2; cUB[tid][3] = b3;
            double shift = (double)cat * 1280.0;
            double x1 = b0 + shift, y1 = b1 + shift;
            double x2 = b2 + shift, y2 = b3 + shift;
            cSX1[tid] = x1; cSY1[tid] = y1; cSX2[tid] = x2; cSY2[tid] = y2;
            cAR2[tid] = (x2 - x1) * (y2 - y1);
            cCat[tid] = cat;
            cMask[tid] = 0ull;
            cSup[tid] = 0;
        }
        __syncthreads();

        // (a) candidates vs accepted list: 16 threads per candidate
        {
            const int i = tid >> 4;
            if (i < n) {
                const int cat = cCat[i];
                const double x1 = cSX1[i], y1 = cSY1[i];
                const double x2 = cSX2[i], y2 = cSY2[i];
                const double areaj = cAR2[i];
                bool f = false;
                for (int r = (tid & 15); r < acc; r += 16) {
                    int cd = aCT[r] - cat; if (cd < 0) cd = -cd;
                    if (cd <= 4) {
                        double ix1 = aX1[r] > x1 ? aX1[r] : x1;
                        double iy1 = aY1[r] > y1 ? aY1[r] : y1;
                        double ix2 = aX2[r] < x2 ? aX2[r] : x2;
                        double iy2 = aY2[r] < y2 ? aY2[r] : y2;
                        double iw = ix2 - ix1; if (iw < 0.0) iw = 0.0;
                        double ih = iy2 - iy1; if (ih < 0.0) ih = 0.0;
                        double inter = iw * ih;
                        double iou = inter / (aAR[r] + areaj - inter + 1e-9);
                        if (iou > 0.5) f = true;
                    }
                }
                if (f) cSup[i] = 1;
            }
        }

        // (b) intra-chunk 64x64 suppression mask (j < i; j as would-be pick)
        for (int p = tid; p < (n << 6); p += NTH) {
            const int i = p >> 6, j = p & 63;
            if (j < i && j < n) {
                int cd = cCat[j] - cCat[i]; if (cd < 0) cd = -cd;
                if (cd <= 4) {
                    double x1 = cSX1[i], y1 = cSY1[i];
                    double x2 = cSX2[i], y2 = cSY2[i];
                    double ix1 = cSX1[j] > x1 ? cSX1[j] : x1;
                    double iy1 = cSY1[j] > y1 ? cSY1[j] : y1;
                    double ix2 = cSX2[j] < x2 ? cSX2[j] : x2;
                    double iy2 = cSY2[j] < y2 ? cSY2[j] : y2;
                    double iw = ix2 - ix1; if (iw < 0.0) iw = 0.0;
                    double ih = iy2 - iy1; if (ih < 0.0) ih = 0.0;
                    double inter = iw * ih;
                    double iou = inter / (cAR2[j] + cAR2[i] - inter + 1e-9);
                    if (iou > 0.5)
                        atomicOr(&cMask[i], 1ull << j);
                }
            }
        }
        __syncthreads();

        // (c) serial 64-bit alive-mask walk (exact greedy order)
        if (tid == 0) {
            unsigned long long am = 0ull;
            int a2 = acc;
            for (int i = 0; i < n && a2 < NOUT; ++i) {
                if (cSup[i]) continue;
                if (cMask[i] & am) continue;
                am |= (1ull << i);
                aX1[a2] = cSX1[i]; aY1[a2] = cSY1[i];
                aX2[a2] = cSX2[i]; aY2[a2] = cSY2[i];
                aAR[a2] = cAR2[i]; aCT[a2] = cCat[i];
                float* o = obuf + a2 * 6;
                o[0] = (float)cUB[i][0]; o[1] = (float)cUB[i][1];
                o[2] = (float)cUB[i][2]; o[3] = (float)cUB[i][3];
                o[4] = (float)__longlong_as_double((long long)skey[c0 + i]);
                o[5] = (float)cCat[i];
                ++a2;
            }
            acc_s = a2;
        }
        __syncthreads();
        acc = acc_s;
    }

    // ---- phase 6: exact fallback (pathological only) -------------------
    if (acc < NOUT && cnt < valid) {
        double* rv = (double*)skey;
        int*    ri = (int*)spay;
        while (acc < NOUT) {
            double best = -1.0;
            int bi = 0x7fffffff;
            for (int j = tid; j < A_TOT; j += NTH) {
                double s = SC[j];
                if (s > 0.0) {
                    int cat = CT[j];
                    const double* bb = BX + (size_t)j * 4;
                    double shift = (double)cat * 1280.0;
                    double x1 = bb[0] + shift, y1 = bb[1] + shift;
                    double x2 = bb[2] + shift, y2 = bb[3] + shift;
                    double areaj = (x2 - x1) * (y2 - y1);
                    bool dead = false;
                    for (int r = 0; r < acc && !dead; ++r) {
                        int cd = aCT[r] - cat; if (cd < 0) cd = -cd;
                        if (cd <= 4) {
                            double ix1 = aX1[r] > x1 ? aX1[r] : x1;
                            double iy1 = aY1[r] > y1 ? aY1[r] : y1;
                            double ix2 = aX2[r] < x2 ? aX2[r] : x2;
                            double iy2 = aY2[r] < y2 ? aY2[r] : y2;
                            double iw = ix2 - ix1; if (iw < 0.0) iw = 0.0;
                            double ih = iy2 - iy1; if (ih < 0.0) ih = 0.0;
                            double inter = iw * ih;
                            double iou = inter / (aAR[r] + areaj - inter + 1e-9);
                            if (iou > 0.5) dead = true;
                        }
                    }
                    if (!dead && s > best) { best = s; bi = j; }
                }
            }
            rv[tid] = best; ri[tid] = bi;
            __syncthreads();
            for (int off = NTH / 2; off > 0; off >>= 1) {
                if (tid < off) {
                    if (rv[tid + off] > rv[tid] ||
                        (rv[tid + off] == rv[tid] && ri[tid + off] < ri[tid])) {
                        rv[tid] = rv[tid + off]; ri[tid] = ri[tid + off];
                    }
                }
                __syncthreads();
            }
            if (rv[0] <= 0.0) break;
            if (tid == 0) {
                int j = ri[0];
                int cat = CT[j];
                const double* bb = BX + (size_t)j * 4;
                double shift = (double)cat * 1280.0;
                double x1 = bb[0] + shift, y1 = bb[1] + shift;
                double x2 = bb[2] + shift, y2 = bb[3] + shift;
                aX1[acc] = x1; aY1[acc] = y1; aX2[acc] = x2; aY2[acc] = y2;
                aAR[acc] = (x2 - x1) * (y2 - y1); aCT[acc] = cat;
                float* o = obuf + acc * 6;
                o[0] = (float)bb[0]; o[1] = (float)bb[1];
                o[2] = (float)bb[2]; o[3] = (float)bb[3];
                o[4] = (float)rv[0]; o[5] = (float)cat;
                acc_s = acc + 1;
            }
            __syncthreads();
            acc = acc_s;
        }
    }
    __syncthreads();

    // ---- phase 7: write output -----------------------------------------
    float* O = out + (size_t)b * NOUT * 6;
    for (int i = tid; i < NOUT * 6; i += NTH) O[i] = obuf[i];
}

extern "C" void kernel_launch(void* const* d_in, const int* in_sizes, int n_in,
                              void* d_out, int out_size, void* d_ws, size_t ws_size,
                              hipStream_t stream)
{
    const float* anchors = (const float*)d_in[10];

    char* ws = (char*)d_ws;
    double* scores = (double*)ws;                                   // 8*A_PAD*8
    int*    cats   = (int*)(ws + (size_t)NBATCH * A_PAD * 8);       // 8*A_PAD*4
    double* boxes  = (double*)(ws + (size_t)NBATCH * A_PAD * 12);   // 8*A_PAD*32

    prep_kernel<<<dim3(12, NANCH, NBATCH), 256, 0, stream>>>(
        (const float*)d_in[0], (const float*)d_in[1],
        (const float*)d_in[2], (const float*)d_in[3],
        (const float*)d_in[4], (const float*)d_in[5],
        (const float*)d_in[6], (const float*)d_in[7],
        (const float*)d_in[8], (const float*)d_in[9],
        anchors, scores, cats, boxes);

    nms_kernel<<<NBATCH, NTH, 0, stream>>>(scores, cats, boxes, (float*)d_out);
}

// Round 5
// 488.981 us; speedup vs baseline: 18.4651x; 1.0207x over previous
//
#include <hip/hip_runtime.h>
#include <cmath>

#define A_TOT 76725
#define A_PAD 76728   // multiple of 4
#define NBATCH 8
#define NCLS 80
#define NANCH 9
#define NOUT 200

#define MCAP 1024     // compacted-candidate capacity (power of two, bitonic)
#define NTH 1024
#define NBUCK 4096
#define CHUNK 64
#define NSLC 32       // parallel slices per batch for hist/compact
#define UKEY_BASE 0x3FE33333u   // upper32 bits of f64(0.6)

// ---------------------------------------------------------------------------
// shared f64 emit: sigmoid + threshold + box decode, identical expressions to
// rounds 1-4 (absmax 0.0 vs np ref) — do not reorder these ops.
// ---------------------------------------------------------------------------
__device__ __forceinline__ void emit_anchor(const float* __restrict__ anchors,
                                            double* __restrict__ scores,
                                            int* __restrict__ cats,
                                            double* __restrict__ boxes,
                                            int b, int arow, float mv, int mc,
                                            float f0, float f1, float f2, float f3)
{
    double sg = 1.0 / (1.0 + exp(-(double)mv));
    double key = (sg >= 0.6) ? sg : -1.0;

    double d0 = (double)f0, d1 = (double)f1, d2 = (double)f2, d3 = (double)f3;

    const float4 av = *(const float4*)(anchors + (size_t)arow * 4);
    double ax1 = (double)av.x, ay1 = (double)av.y;
    double ax2 = (double)av.z, ay2 = (double)av.w;
    double aw = ax2 - ax1, ah = ay2 - ay1;
    double acx = ax1 + 0.5 * aw, acy = ay1 + 0.5 * ah;
    double cx = acx + d0 * aw, cy = acy + d1 * ah;
    double w = aw * exp(d2), h = ah * exp(d3);

    size_t o = (size_t)b * A_PAD + arow;
    scores[o] = key;
    cats[o] = mc;
    double* bxp = boxes + o * 4;
    bxp[0] = cx - 0.5 * w;
    bxp[1] = cy - 0.5 * h;
    bxp[2] = cx + 0.5 * w;
    bxp[3] = cy + 0.5 * h;
}

// ---------------------------------------------------------------------------
// fused prep: grid (12 chunks, 9 anchors, 8 batch), 256 thr; thread = 4 locs.
// (byte-identical to rounds 3/4 for attribution)
// ---------------------------------------------------------------------------
__global__ void prep_kernel(const float* __restrict__ lg0, const float* __restrict__ rg0,
                            const float* __restrict__ lg1, const float* __restrict__ rg1,
                            const float* __restrict__ lg2, const float* __restrict__ rg2,
                            const float* __restrict__ lg3, const float* __restrict__ rg3,
                            const float* __restrict__ lg4, const float* __restrict__ rg4,
                            const float* __restrict__ anchors,
                            double* __restrict__ scores,
                            int* __restrict__ cats,
                            double* __restrict__ boxes)
{
    const int bx = blockIdx.x;
    const int a  = blockIdx.y;
    const int b  = blockIdx.z;
    int lvl, chunk;
    if (bx < 7)      { lvl = 0; chunk = bx; }
    else if (bx < 9) { lvl = 1; chunk = bx - 7; }
    else             { lvl = bx - 7; chunk = 0; }

    const int   sarr[5] = {6400, 1600, 400, 100, 25};
    const int   barr[5] = {0, 57600, 72000, 75600, 76500};
    const float* lgs[5] = {lg0, lg1, lg2, lg3, lg4};
    const float* rgs[5] = {rg0, rg1, rg2, rg3, rg4};
    const int s = sarr[lvl], base = barr[lvl];
    const float* lg = lgs[lvl];
    const float* rg = rgs[lvl];

    const int loc0 = chunk * 1024 + threadIdx.x * 4;
    if (loc0 >= s) return;

    const float* lga = lg + ((size_t)(b * NANCH + a) * NCLS) * s + loc0;
    const float* rga = rg + ((size_t)(b * NANCH + a) * 4) * s + loc0;

    if ((s & 3) == 0) {
        float4 m = *(const float4*)lga;
        int mcx = 0, mcy = 0, mcz = 0, mcw = 0;
        #pragma unroll 8
        for (int c = 1; c < NCLS; ++c) {
            float4 v = *(const float4*)(lga + (size_t)c * s);
            if (v.x > m.x) { m.x = v.x; mcx = c; }
            if (v.y > m.y) { m.y = v.y; mcy = c; }
            if (v.z > m.z) { m.z = v.z; mcz = c; }
            if (v.w > m.w) { m.w = v.w; mcw = c; }
        }
        float4 r0 = *(const float4*)(rga);
        float4 r1 = *(const float4*)(rga + (size_t)s);
        float4 r2 = *(const float4*)(rga + 2 * (size_t)s);
        float4 r3 = *(const float4*)(rga + 3 * (size_t)s);

        const float* mp  = (const float*)&m;
        const int    mci[4] = {mcx, mcy, mcz, mcw};
        const float* p0 = (const float*)&r0;
        const float* p1 = (const float*)&r1;
        const float* p2 = (const float*)&r2;
        const float* p3 = (const float*)&r3;
        #pragma unroll
        for (int j = 0; j < 4; ++j) {
            const int arow = base + (loc0 + j) * NANCH + a;
            emit_anchor(anchors, scores, cats, boxes, b, arow,
                        mp[j], mci[j], p0[j], p1[j], p2[j], p3[j]);
        }
    } else {
        for (int j = 0; j < 4; ++j) {
            const int loc = loc0 + j;
            if (loc >= s) break;
            const float* l1 = lga + j;
            float mv = l1[0];
            int mc = 0;
            #pragma unroll 8
            for (int c = 1; c < NCLS; ++c) {
                float v = l1[(size_t)c * s];
                if (v > mv) { mv = v; mc = c; }
            }
            const float* r1 = rga + j;
            const int arow = base + loc * NANCH + a;
            emit_anchor(anchors, scores, cats, boxes, b, arow, mv, mc,
                        r1[0], r1[(size_t)s], r1[2 * (size_t)s], r1[3 * (size_t)s]);
        }
    }
}

// ---------------------------------------------------------------------------
// hist: (NSLC, NBATCH) x 256. Per-block LDS histogram of score-key upper
// bits, then global atomic merge (skip zero bins). hist pre-zeroed by memset.
// ---------------------------------------------------------------------------
__global__ void hist_kernel(const double* __restrict__ scores,
                            unsigned* __restrict__ hist)
{
    const int b = blockIdx.y;
    const int tid = threadIdx.x;
    const double* SC = scores + (size_t)b * A_PAD;
    __shared__ unsigned lh[NBUCK];
    for (int i = tid; i < NBUCK; i += 256) lh[i] = 0u;
    __syncthreads();
    const int stride = NSLC * 256;
    for (int j = blockIdx.x * 256 + tid; j < A_TOT; j += stride) {
        double s = SC[j];
        if (s > 0.0) {
            unsigned uk = (unsigned)((unsigned long long)__double_as_longlong(s) >> 32);
            atomicAdd(&lh[(uk - UKEY_BASE) >> 8], 1u);
        }
    }
    __syncthreads();
    unsigned* H = hist + (size_t)b * NBUCK;
    for (int i = tid; i < NBUCK; i += 256) {
        unsigned v = lh[i];
        if (v) atomicAdd(&H[i], v);
    }
}

// ---------------------------------------------------------------------------
// select: per-batch suffix scan of hist -> threshold bucket bstar such that
// suffix count <= MCAP (bstar = NBUCK if even the top bucket overflows ->
// cnt 0 -> exact fallback path).
// ---------------------------------------------------------------------------
__global__ void select_kernel(const unsigned* __restrict__ hist,
                              int* __restrict__ bstar,
                              int* __restrict__ validc)
{
    const int b = blockIdx.x;
    const int tid = threadIdx.x;
    __shared__ unsigned sa[NBUCK], sb[NBUCK];
    __shared__ int bs_s;
    const unsigned* H = hist + (size_t)b * NBUCK;
    for (int i = tid; i < NBUCK; i += NTH) sa[i] = H[i];
    if (tid == 0) bs_s = NBUCK;
    __syncthreads();
    unsigned* src = sa; unsigned* dst = sb;
    for (int off = 1; off < NBUCK; off <<= 1) {
        for (int i = tid; i < NBUCK; i += NTH)
            dst[i] = src[i] + ((i + off < NBUCK) ? src[i + off] : 0u);
        __syncthreads();
        unsigned* t = src; src = dst; dst = t;
    }
    for (int i = tid; i < NBUCK; i += NTH) {
        if (src[i] <= (unsigned)MCAP && (i == 0 || src[i - 1] > (unsigned)MCAP))
            bs_s = i;
    }
    __syncthreads();
    if (tid == 0) { bstar[b] = bs_s; validc[b] = (int)src[0]; }
}

// ---------------------------------------------------------------------------
// compact: (NSLC, NBATCH) x 256. Append candidates with bucket >= bstar to
// per-batch global buffer. Selection invariant guarantees count <= MCAP.
// ccount pre-zeroed by memset.
// ---------------------------------------------------------------------------
__global__ void compact_kernel(const double* __restrict__ scores,
                               const int* __restrict__ cats,
                               const int* __restrict__ bstar,
                               unsigned long long* __restrict__ ckey,
                               unsigned* __restrict__ cpay,
                               int* __restrict__ ccount)
{
    const int b = blockIdx.y;
    const int tid = threadIdx.x;
    const double* SC = scores + (size_t)b * A_PAD;
    const int* CT = cats + (size_t)b * A_PAD;
    const int bs = bstar[b];
    const int stride = NSLC * 256;
    for (int j = blockIdx.x * 256 + tid; j < A_TOT; j += stride) {
        double s = SC[j];
        if (s > 0.0) {
            long long bits = __double_as_longlong(s);
            unsigned uk = (unsigned)((unsigned long long)bits >> 32);
            int bk = (int)((uk - UKEY_BASE) >> 8);
            if (bk >= bs) {
                int p = atomicAdd(&ccount[b], 1);
                if (p < MCAP) {
                    ckey[(size_t)b * MCAP + p] = (unsigned long long)bits;
                    cpay[(size_t)b * MCAP + p] = ((unsigned)j << 7) | (unsigned)CT[j];
                }
            }
        }
    }
}

// ---------------------------------------------------------------------------
// greedy: one block per batch. Bitonic sort (key desc, payload asc) of the
// compacted candidates, then round-4's chunk-parallel greedy sorted scan
// (== reference iterative argmax+suppress incl. first-index tie-break),
// then exact fallback for pathological cases. f64 IoU verbatim.
// ---------------------------------------------------------------------------
__launch_bounds__(NTH, 1)
__global__ void greedy_kernel(const double* __restrict__ scores,
                              const int* __restrict__ cats,
                              const double* __restrict__ boxes,
                              const unsigned long long* __restrict__ ckey,
                              const unsigned* __restrict__ cpay,
                              const int* __restrict__ ccount,
                              const int* __restrict__ validc,
                              float* __restrict__ out)
{
    const int b = blockIdx.x;
    const int tid = threadIdx.x;
    const double* SC = scores + (size_t)b * A_PAD;
    const int*    CT = cats + (size_t)b * A_PAD;
    const double* BX = boxes + (size_t)b * A_PAD * 4;

    __shared__ unsigned long long skey[MCAP];   // 8 KB (reused as rv[] in fallback)
    __shared__ unsigned spay[MCAP];             // 4 KB  (reused as ri[] in fallback)
    __shared__ alignas(16) char ubuf[32768];
    __shared__ int acc_s;

    const int cnt_raw = ccount[b];
    const int cnt = cnt_raw < MCAP ? cnt_raw : MCAP;
    const int valid = validc[b];

    for (int i = tid; i < MCAP; i += NTH) {
        if (i < cnt) {
            skey[i] = ckey[(size_t)b * MCAP + i];
            spay[i] = cpay[(size_t)b * MCAP + i];
        } else {
            skey[i] = 0ull;
            spay[i] = 0xFFFFFFFFu;
        }
    }
    __syncthreads();

    // ---- bitonic sort (key desc, payload asc) --------------------------
    for (int k = 2; k <= MCAP; k <<= 1) {
        for (int j = k >> 1; j > 0; j >>= 1) {
            for (int i = tid; i < MCAP; i += NTH) {
                int ixj = i ^ j;
                if (ixj > i) {
                    unsigned long long ka = skey[i], kb = skey[ixj];
                    unsigned pa = spay[i], pb = spay[ixj];
                    bool before = (ka > kb) || (ka == kb && pa < pb);
                    bool dir = ((i & k) == 0);
                    if (before != dir) {
                        skey[i] = kb; skey[ixj] = ka;
                        spay[i] = pb; spay[ixj] = pa;
                    }
                }
            }
            __syncthreads();
        }
    }

    // ---- LDS layout for accepted/out/chunk -----------------------------
    double* aX1 = (double*)ubuf;                           // 200*8*5 = 8000
    double* aY1 = aX1 + NOUT;
    double* aX2 = aY1 + NOUT;
    double* aY2 = aX2 + NOUT;
    double* aAR = aY2 + NOUT;
    int*   aCT  = (int*)(ubuf + 8000);                     // 800
    float* obuf = (float*)(ubuf + 8800);                   // 4800
    double* cSX1 = (double*)(ubuf + 13600);                // 64*8 each
    double* cSY1 = (double*)(ubuf + 14112);
    double* cSX2 = (double*)(ubuf + 14624);
    double* cSY2 = (double*)(ubuf + 15136);
    double* cAR2 = (double*)(ubuf + 15648);
    double (*cUB)[4] = (double(*)[4])(ubuf + 16160);       // 64*32 = 2048
    int* cCat = (int*)(ubuf + 18208);                      // 256
    unsigned long long* cMask = (unsigned long long*)(ubuf + 18464);  // 512
    int* cSup = (int*)(ubuf + 18976);                      // 256

    for (int i = tid; i < NOUT * 6; i += NTH)
        obuf[i] = ((i % 6) == 5) ? -1.0f : 0.0f;
    __syncthreads();

    // ---- chunk-parallel greedy sorted scan -----------------------------
    int acc = 0;
    for (int c0 = 0; c0 < cnt && acc < NOUT; c0 += CHUNK) {
        const int n = (cnt - c0) < CHUNK ? (cnt - c0) : CHUNK;

        if (tid < n) {
            unsigned pay = spay[c0 + tid];
            int idx = (int)(pay >> 7);
            int cat = (int)(pay & 127u);
            const double* bb = BX + (size_t)idx * 4;
            double b0 = bb[0], b1 = bb[1], b2 = bb[2], b3 = bb[3];
            cUB[tid][0] = b0; cUB[tid][1] = b1; cUB[tid][2] = b2; cUB[tid][3] = b3;
            double shift = (double)cat * 1280.0;
            double x1 = b0 + shift, y1 = b1 + shift;
            double x2 = b2 + shift, y2 = b3 + shift;
            cSX1[tid] = x1; cSY1[tid] = y1; cSX2[tid] = x2; cSY2[tid] = y2;
            cAR2[tid] = (x2 - x1) * (y2 - y1);
            cCat[tid] = cat;
            cMask[tid] = 0ull;
            cSup[tid] = 0;
        }
        __syncthreads();

        // (a) candidates vs accepted list: 16 threads per candidate
        {
            const int i = tid >> 4;
            if (i < n) {
                const int cat = cCat[i];
                const double x1 = cSX1[i], y1 = cSY1[i];
                const double x2 = cSX2[i], y2 = cSY2[i];
                const double areaj = cAR2[i];
                bool f = false;
                for (int r = (tid & 15); r < acc; r += 16) {
                    int cd = aCT[r] - cat; if (cd < 0) cd = -cd;
                    if (cd <= 4) {
                        double ix1 = aX1[r] > x1 ? aX1[r] : x1;
                        double iy1 = aY1[r] > y1 ? aY1[r] : y1;
                        double ix2 = aX2[r] < x2 ? aX2[r] : x2;
                        double iy2 = aY2[r] < y2 ? aY2[r] : y2;
                        double iw = ix2 - ix1; if (iw < 0.0) iw = 0.0;
                        double ih = iy2 - iy1; if (ih < 0.0) ih = 0.0;
                        double inter = iw * ih;
                        double iou = inter / (aAR[r] + areaj - inter + 1e-9);
                        if (iou > 0.5) f = true;
                    }
                }
                if (f) cSup[i] = 1;
            }
        }

        // (b) intra-chunk 64x64 suppression mask (j < i; j as would-be pick)
        for (int p = tid; p < (n << 6); p += NTH) {
            const int i = p >> 6, j = p & 63;
            if (j < i && j < n) {
                int cd = cCat[j] - cCat[i]; if (cd < 0) cd = -cd;
                if (cd <= 4) {
                    double x1 = cSX1[i], y1 = cSY1[i];
                    double x2 = cSX2[i], y2 = cSY2[i];
                    double ix1 = cSX1[j] > x1 ? cSX1[j] : x1;
                    double iy1 = cSY1[j] > y1 ? cSY1[j] : y1;
                    double ix2 = cSX2[j] < x2 ? cSX2[j] : x2;
                    double iy2 = cSY2[j] < y2 ? cSY2[j] : y2;
                    double iw = ix2 - ix1; if (iw < 0.0) iw = 0.0;
                    double ih = iy2 - iy1; if (ih < 0.0) ih = 0.0;
                    double inter = iw * ih;
                    double iou = inter / (cAR2[j] + cAR2[i] - inter + 1e-9);
                    if (iou > 0.5)
                        atomicOr(&cMask[i], 1ull << j);
                }
            }
        }
        __syncthreads();

        // (c) serial 64-bit alive-mask walk (exact greedy order)
        if (tid == 0) {
            unsigned long long am = 0ull;
            int a2 = acc;
            for (int i = 0; i < n && a2 < NOUT; ++i) {
                if (cSup[i]) continue;
                if (cMask[i] & am) continue;
                am |= (1ull << i);
                aX1[a2] = cSX1[i]; aY1[a2] = cSY1[i];
                aX2[a2] = cSX2[i]; aY2[a2] = cSY2[i];
                aAR[a2] = cAR2[i]; aCT[a2] = cCat[i];
                float* o = obuf + a2 * 6;
                o[0] = (float)cUB[i][0]; o[1] = (float)cUB[i][1];
                o[2] = (float)cUB[i][2]; o[3] = (float)cUB[i][3];
                o[4] = (float)__longlong_as_double((long long)skey[c0 + i]);
                o[5] = (float)cCat[i];
                ++a2;
            }
            acc_s = a2;
        }
        __syncthreads();
        acc = acc_s;
    }

    // ---- exact fallback (pathological only) ----------------------------
    if (acc < NOUT && cnt < valid) {
        double* rv = (double*)skey;
        int*    ri = (int*)spay;
        while (acc < NOUT) {
            double best = -1.0;
            int bi = 0x7fffffff;
            for (int j = tid; j < A_TOT; j += NTH) {
                double s = SC[j];
                if (s > 0.0) {
                    int cat = CT[j];
                    const double* bb = BX + (size_t)j * 4;
                    double shift = (double)cat * 1280.0;
                    double x1 = bb[0] + shift, y1 = bb[1] + shift;
                    double x2 = bb[2] + shift, y2 = bb[3] + shift;
                    double areaj = (x2 - x1) * (y2 - y1);
                    bool dead = false;
                    for (int r = 0; r < acc && !dead; ++r) {
                        int cd = aCT[r] - cat; if (cd < 0) cd = -cd;
                        if (cd <= 4) {
                            double ix1 = aX1[r] > x1 ? aX1[r] : x1;
                            double iy1 = aY1[r] > y1 ? aY1[r] : y1;
                            double ix2 = aX2[r] < x2 ? aX2[r] : x2;
                            double iy2 = aY2[r] < y2 ? aY2[r] : y2;
                            double iw = ix2 - ix1; if (iw < 0.0) iw = 0.0;
                            double ih = iy2 - iy1; if (ih < 0.0) ih = 0.0;
                            double inter = iw * ih;
                            double iou = inter / (aAR[r] + areaj - inter + 1e-9);
                            if (iou > 0.5) dead = true;
                        }
                    }
                    if (!dead && s > best) { best = s; bi = j; }
                }
            }
            rv[tid] = best; ri[tid] = bi;
            __syncthreads();
            for (int off = NTH / 2; off > 0; off >>= 1) {
                if (tid < off) {
                    if (rv[tid + off] > rv[tid] ||
                        (rv[tid + off] == rv[tid] && ri[tid + off] < ri[tid])) {
                        rv[tid] = rv[tid + off]; ri[tid] = ri[tid + off];
                    }
                }
                __syncthreads();
            }
            if (rv[0] <= 0.0) break;
            if (tid == 0) {
                int j = ri[0];
                int cat = CT[j];
                const double* bb = BX + (size_t)j * 4;
                double shift = (double)cat * 1280.0;
                double x1 = bb[0] + shift, y1 = bb[1] + shift;
                double x2 = bb[2] + shift, y2 = bb[3] + shift;
                aX1[acc] = x1; aY1[acc] = y1; aX2[acc] = x2; aY2[acc] = y2;
                aAR[acc] = (x2 - x1) * (y2 - y1); aCT[acc] = cat;
                float* o = obuf + acc * 6;
                o[0] = (float)bb[0]; o[1] = (float)bb[1];
                o[2] = (float)bb[2]; o[3] = (float)bb[3];
                o[4] = (float)rv[0]; o[5] = (float)cat;
                acc_s = acc + 1;
            }
            __syncthreads();
            acc = acc_s;
        }
    }
    __syncthreads();

    // ---- write output ---------------------------------------------------
    float* O = out + (size_t)b * NOUT * 6;
    for (int i = tid; i < NOUT * 6; i += NTH) O[i] = obuf[i];
}

extern "C" void kernel_launch(void* const* d_in, const int* in_sizes, int n_in,
                              void* d_out, int out_size, void* d_ws, size_t ws_size,
                              hipStream_t stream)
{
    const float* anchors = (const float*)d_in[10];

    char* ws = (char*)d_ws;
    double* scores = (double*)ws;                                   // 8*A_PAD*8
    int*    cats   = (int*)(ws + (size_t)NBATCH * A_PAD * 8);       // 8*A_PAD*4
    double* boxes  = (double*)(ws + (size_t)NBATCH * A_PAD * 12);   // 8*A_PAD*32

    size_t off = (size_t)NBATCH * A_PAD * 44;                        // 27,008,256
    unsigned* hist = (unsigned*)(ws + off);                          // 131072
    int* ccount = (int*)(ws + off + 131072);                         // 32
    int* bstar  = (int*)(ws + off + 131104);                         // 32
    int* validc = (int*)(ws + off + 131136);                         // 32
    unsigned long long* ckey = (unsigned long long*)(ws + off + 131200); // 65536
    unsigned* cpay = (unsigned*)(ws + off + 131200 + 65536);         // 32768

    // zero hist + ccount (contiguous region)
    hipMemsetAsync(hist, 0, 131072 + 32, stream);

    prep_kernel<<<dim3(12, NANCH, NBATCH), 256, 0, stream>>>(
        (const float*)d_in[0], (const float*)d_in[1],
        (const float*)d_in[2], (const float*)d_in[3],
        (const float*)d_in[4], (const float*)d_in[5],
        (const float*)d_in[6], (const float*)d_in[7],
        (const float*)d_in[8], (const float*)d_in[9],
        anchors, scores, cats, boxes);

    hist_kernel<<<dim3(NSLC, NBATCH), 256, 0, stream>>>(scores, hist);
    select_kernel<<<NBATCH, NTH, 0, stream>>>(hist, bstar, validc);
    compact_kernel<<<dim3(NSLC, NBATCH), 256, 0, stream>>>(
        scores, cats, bstar, ckey, cpay, ccount);
    greedy_kernel<<<NBATCH, NTH, 0, stream>>>(
        scores, cats, boxes, ckey, cpay, ccount, validc, (float*)d_out);
}